// Round 1
// baseline (476.765 us; speedup 1.0000x reference)
//
#include <hip/hip_runtime.h>

// PatchEmbed: x (16,64,256,256) f32 -> out (16, 64*64, 64*4*4) f32 + ori_shape tail.
// out[n][wp*HP+hp][c*16+pi*4+pj] = x[n][c][hp*4+pi][wp*4+pj]
// One thread per (n,c,hp,wp): 4 coalesced float4 reads (row-strided in x),
// 4 contiguous float4 writes = one full 64B line in out.

constexpr int N  = 16;
constexpr int C  = 64;
constexpr int H  = 256;
constexpr int W  = 256;
constexpr int P  = 4;
constexpr int HP = H / P;   // 64
constexpr int WP = W / P;   // 64
constexpr int W4 = W / 4;   // 64 float4s per input row

__global__ __launch_bounds__(256) void patch_embed_kernel(
    const float* __restrict__ x, float* __restrict__ out)
{
    const int t = blockIdx.x * 256 + threadIdx.x;
    // Consecutive threads -> consecutive wp (coalesced input reads).
    const int wp = t & 63;
    const int hp = (t >> 6) & 63;
    const int c  = (t >> 12) & 63;
    const int n  = t >> 18;

    const float4* __restrict__ x4 = (const float4*)x;
    float4* __restrict__ o4       = (float4*)out;

    // Input float4 index: ((n*C + c)*H + hp*4 + pi) * W4 + wp
    const long bin = ((long)((n * C + c) * H + hp * P)) * W4 + wp;
    // Output float4 index: (n*WP*HP + wp*HP + hp) * (C*P*P/4) + c*4 + pi
    const long bout = ((long)(n * (WP * HP) + wp * HP + hp)) * (C * P * P / 4) + c * 4;

    float4 r0 = x4[bin + 0 * W4];
    float4 r1 = x4[bin + 1 * W4];
    float4 r2 = x4[bin + 2 * W4];
    float4 r3 = x4[bin + 3 * W4];
    o4[bout + 0] = r0;
    o4[bout + 1] = r1;
    o4[bout + 2] = r2;
    o4[bout + 3] = r3;
}

// Second tuple output: ori_shape = (N, C, H, W) as int32; the concatenated
// output buffer is read back as f32, so store the values as floats.
__global__ void tail_kernel(float* __restrict__ out, int off)
{
    if (threadIdx.x == 0) {
        out[off + 0] = (float)N;
        out[off + 1] = (float)C;
        out[off + 2] = (float)H;
        out[off + 3] = (float)W;
    }
}

extern "C" void kernel_launch(void* const* d_in, const int* in_sizes, int n_in,
                              void* d_out, int out_size, void* d_ws, size_t ws_size,
                              hipStream_t stream)
{
    const float* x = (const float*)d_in[0];
    float* out     = (float*)d_out;

    const int total  = N * C * HP * WP;        // 4,194,304 threads
    const int blocks = total / 256;            // 16,384 blocks

    patch_embed_kernel<<<blocks, 256, 0, stream>>>(x, out);
    tail_kernel<<<1, 64, 0, stream>>>(out, out_size - 4);
}

// Round 2
// 432.933 us; speedup vs baseline: 1.1012x; 1.1012x over previous
//
#include <hip/hip_runtime.h>

// PatchEmbed: x (16,64,256,256) f32 -> out (16, 64*64, 64*4*4) f32 + ori_shape tail.
// out[n][wp*HP+hp][c*16+pi*4+pj] = x[n][c][hp*4+pi][wp*4+pj]
//
// Round 1 was store-bound: each store instr scattered 64x16B across lines
// 256 KiB apart (2.48 TB/s). This version stages a (n, hp, 16-wp) tile
// through 64 KB of LDS so every global store instruction is 1 KiB
// contiguous (tokens written as whole 4 KiB streams) and every load instr
// is 4x 256 B segments. XOR swizzle (c4pi ^ v) keeps LDS conflict-free
// without padding, so the tile is exactly 64 KB -> 2 blocks/CU.

constexpr int N  = 16;
constexpr int C  = 64;
constexpr int H  = 256;
constexpr int W  = 256;
constexpr int P  = 4;
constexpr int HP = H / P;     // 64
constexpr int WP = W / P;     // 64
constexpr int W4 = W / 4;     // 64 float4 per input row (1 float4 == 1 wp's pj-quad)
constexpr int WT = 16;        // wp values per block
constexpr int TOK4 = C * P * P / 4;  // 256 float4 per output token (4 KiB)

__global__ __launch_bounds__(512) void patch_embed_kernel(
    const float4* __restrict__ x4, float4* __restrict__ o4)
{
    // lds[v][c4pi ^ v] : v = wp within tile (16 tokens), c4pi = c*4+pi (256)
    __shared__ float4 lds[WT * TOK4];   // 65536 B exactly

    const int t   = threadIdx.x;        // 0..511
    const int bid = blockIdx.x;         // 0..4095
    const int wt  = bid & 3;
    const int hp  = (bid >> 2) & 63;
    const int n   = bid >> 8;
    const int wp0 = wt * WT;

    // ---- Phase 1: global -> LDS (8 float4 / thread) ----
    // f = i*512 + t ; c4pi = f>>4 ; v = f&15
    // per wave: 4 consecutive c4pi (= 4 rows of one c), 16 consecutive wp each
    //   -> 4 x 256 B contiguous global segments per instruction
#pragma unroll
    for (int i = 0; i < 8; ++i) {
        const int f    = i * 512 + t;
        const int c4pi = f >> 4;            // 0..255
        const int v    = f & 15;            // wp - wp0
        const int c    = c4pi >> 2;
        const int pi   = c4pi & 3;
        const int in_idx = ((n * C + c) * H + hp * P + pi) * W4 + wp0 + v;
        lds[v * TOK4 + (c4pi ^ v)] = x4[in_idx];
    }

    __syncthreads();

    // ---- Phase 2: LDS -> global (8 float4 / thread) ----
    // g = i*512 + t ; v = g>>8 ; j = g&255
    // per wave: 64 consecutive float4 -> 1 KiB contiguous global store;
    // each token = 4 KiB written whole.
#pragma unroll
    for (int i = 0; i < 8; ++i) {
        const int g = i * 512 + t;
        const int v = g >> 8;               // token within tile
        const int j = g & 255;              // float4 within token
        const int out_idx = (n * (WP * HP) + (wp0 + v) * HP + hp) * TOK4 + j;
        o4[out_idx] = lds[v * TOK4 + (j ^ v)];
    }
}

// Second tuple output: ori_shape = (N, C, H, W); output buffer is read back
// as f32, so store the values as floats.
__global__ void tail_kernel(float* __restrict__ out, int off)
{
    if (threadIdx.x == 0) {
        out[off + 0] = (float)N;
        out[off + 1] = (float)C;
        out[off + 2] = (float)H;
        out[off + 3] = (float)W;
    }
}

extern "C" void kernel_launch(void* const* d_in, const int* in_sizes, int n_in,
                              void* d_out, int out_size, void* d_ws, size_t ws_size,
                              hipStream_t stream)
{
    const float4* x4 = (const float4*)d_in[0];
    float4* o4       = (float4*)d_out;
    float* out       = (float*)d_out;

    const int blocks = N * HP * (WP / WT);   // 16 * 64 * 4 = 4096
    patch_embed_kernel<<<blocks, 512, 0, stream>>>(x4, o4);
    tail_kernel<<<1, 64, 0, stream>>>(out, out_size - 4);
}